// Round 6
// baseline (336.792 us; speedup 1.0000x reference)
//
#include <hip/hip_runtime.h>
#include <stdint.h>

#define TOKS 2048
#define SEQ 1024

typedef __attribute__((ext_vector_type(8))) short short8;
typedef __attribute__((ext_vector_type(4))) short short4v;
typedef __attribute__((ext_vector_type(4))) float f32x4;

// ---------------- dtype helpers ----------------
__device__ __forceinline__ float loadf(const void* p, size_t i, int isbf16) {
  if (isbf16) {
    unsigned short u = ((const unsigned short*)p)[i];
    return __uint_as_float(((unsigned)u) << 16);
  }
  return ((const float*)p)[i];
}
__device__ __forceinline__ unsigned short f32_to_bf16(float f) {
  unsigned u = __float_as_uint(f);
  unsigned r = u + 0x7FFFu + ((u >> 16) & 1u);
  return (unsigned short)(r >> 16);
}
__device__ __forceinline__ float bf2f(unsigned short u) {
  return __uint_as_float(((unsigned)u) << 16);
}
__device__ __forceinline__ unsigned pk2bf(float a, float b) {
  return ((unsigned)f32_to_bf16(b) << 16) | (unsigned)f32_to_bf16(a);
}

// ---------------- detection ----------------
__global__ void k_detect(const void* fs, const void* bs, int* flags) {
  int lane = threadIdx.x;
  int bad = 0;
  for (int i = lane; i < 256; i += 64) {
    unsigned short u = ((const unsigned short*)fs)[i];
    float v = __uint_as_float(((unsigned)u) << 16);
    if (!(fabsf(v) <= 100.f)) bad = 1;
  }
  int big = 0;
  for (int i = lane; i < 512; i += 64) {
    if (((const unsigned*)bs)[i] > 1u) big = 1;
  }
#pragma unroll
  for (int off = 32; off; off >>= 1) {
    bad |= __shfl_xor(bad, off);
    big |= __shfl_xor(big, off);
  }
  if (lane == 0) { flags[0] = bad ? 0 : 1; flags[1] = big ? 1 : 0; }
}

// ---------------- canonicalization ----------------
struct ConvEntry { const void* src; float* dst; int n; };
struct ConvArgs { ConvEntry e[21]; };

__global__ void k_convert_many(ConvArgs ca, const int* __restrict__ flags) {
  int isbf = flags[0];
  ConvEntry E = ca.e[blockIdx.y];
  for (int i = blockIdx.x * 256 + threadIdx.x; i < E.n; i += gridDim.x * 256)
    E.dst[i] = loadf(E.src, (size_t)i, isbf);
}

__global__ void k_conv_bf(const void* src, unsigned short* __restrict__ dst,
                          int n, const int* __restrict__ flags) {
  int isbf = flags[0];
  int i = (blockIdx.x * 256 + threadIdx.x) * 4;
  if (i < n) {
#pragma unroll
    for (int j = 0; j < 4; j++) dst[i + j] = f32_to_bf16(loadf(src, i + j, isbf));
  }
}

__global__ void k_convert_bools(const void* pad, const void* msk,
                                unsigned char* pb, unsigned char* mb,
                                const int* __restrict__ flags) {
  int isb = flags[1];
  int i = blockIdx.x * 256 + threadIdx.x;
  if (i < TOKS) {
    if (isb) {
      pb[i] = ((const unsigned char*)pad)[i] ? 1 : 0;
      mb[i] = ((const unsigned char*)msk)[i] ? 1 : 0;
    } else {
      pb[i] = (((const int*)pad)[i] != 0) ? 1 : 0;
      mb[i] = (((const int*)msk)[i] != 0) ? 1 : 0;
    }
  }
}

// ---------------- transposed bf16 weight conversion ----------------
struct TEntry { const void* src; unsigned short* dst; int soff, K, N, pitch; };
struct TArgs { TEntry e[38]; };

__global__ __launch_bounds__(256) void k_conv_T(TArgs ta, const int* __restrict__ flags) {
  int isbf = flags[0];
  TEntry E = ta.e[blockIdx.y];
  int ktiles = E.K >> 5, ntiles = E.N >> 5;
  if ((int)blockIdx.x >= ktiles * ntiles) return;
  int tk = blockIdx.x % ktiles, tn = blockIdx.x / ktiles;
  __shared__ float t[32][33];
  int tx = threadIdx.x & 31, ty = threadIdx.x >> 5;
#pragma unroll
  for (int s = 0; s < 4; s++) {
    int k = tk * 32 + ty + s * 8, n = tn * 32 + tx;
    t[ty + s * 8][tx] = loadf(E.src, (size_t)E.soff + (size_t)k * E.N + n, isbf);
  }
  __syncthreads();
#pragma unroll
  for (int s = 0; s < 4; s++) {
    int n = tn * 32 + ty + s * 8, k = tk * 32 + tx;
    E.dst[(size_t)n * E.pitch + k] = f32_to_bf16(t[tx][ty + s * 8]);
  }
}

// ---------------- mask words (transposed for swapped-QK attn) ----------------
// W3m[((z*1024 + q)*16 + kc)*4 + g] : u16, bit (4t+r) = mask(q, key=kc*64+16t+4g+r)
__global__ __launch_bounds__(64) void k_masks3(
    const int* __restrict__ node, const int* __restrict__ f2p,
    const int* __restrict__ colid, const int* __restrict__ tabid,
    const unsigned char* __restrict__ pad_b, unsigned short* __restrict__ W3m) {
  int kc = blockIdx.x, qb = blockIdx.y, z = blockIdx.z;
  int b = z >> 2, l = z & 3;
  int base = b * SEQ;
  int tid = threadIdx.x;
  __shared__ int kn[64], kcl[64], ktb[64], kpd[64], kf2[64][8];
  __shared__ int qn[16], qcl[16], qtb[16], qpd[16], qf2[16][8];

  int kkey = base + kc * 64 + tid;
  kn[tid] = node[kkey];
  kcl[tid] = colid[kkey];
  ktb[tid] = tabid[kkey];
  kpd[tid] = pad_b[kkey] ? 0 : 1;
  if (l == 1) {
#pragma unroll
    for (int j = 0; j < 8; j++) kf2[tid][j] = f2p[(size_t)kkey * 8 + j];
  }
  if (tid < 16) {
    int qq = base + qb * 16 + tid;
    qn[tid] = node[qq]; qcl[tid] = colid[qq]; qtb[tid] = tabid[qq];
    qpd[tid] = pad_b[qq] ? 0 : 1;
  }
  if (l == 0) {
#pragma unroll
    for (int s = 0; s < 2; s++) {
      int i = tid + s * 64;  // 128 q-f2p entries
      qf2[i >> 3][i & 7] = f2p[(size_t)(base + qb * 16 + (i >> 3)) * 8 + (i & 7)];
    }
  }
  __syncthreads();

  int q = tid & 15, g = tid >> 4;
  unsigned w = 0;
#pragma unroll
  for (int t = 0; t < 4; t++) {
#pragma unroll
    for (int r = 0; r < 4; r++) {
      int kl = t * 16 + g * 4 + r;
      int sel;
      if (l == 0) {
        int nk = kn[kl];
        sel = (qn[q] == nk);
#pragma unroll
        for (int j = 0; j < 8; j++) sel |= (qf2[q][j] == nk);
      } else if (l == 1) {
        int n = qn[q];
        sel = (n == kf2[kl][0]) | (n == kf2[kl][1]) | (n == kf2[kl][2]) | (n == kf2[kl][3]) |
              (n == kf2[kl][4]) | (n == kf2[kl][5]) | (n == kf2[kl][6]) | (n == kf2[kl][7]);
      } else if (l == 2) {
        sel = (qcl[q] == kcl[kl]) & (qtb[q] == ktb[kl]);
      } else {
        sel = 1;
      }
      w |= (unsigned)(sel & qpd[q] & kpd[kl]) << (4 * t + r);
    }
  }
  W3m[((size_t)(z * 1024 + qb * 16 + q) * 16 + kc) * 4 + g] = (unsigned short)w;
}

// ---------------- block reductions / LN ----------------
__device__ __forceinline__ float block_sum256(float v, float* red) {
#pragma unroll
  for (int off = 32; off; off >>= 1) v += __shfl_xor(v, off);
  int w = threadIdx.x >> 6;
  __syncthreads();
  if ((threadIdx.x & 63) == 0) red[w] = v;
  __syncthreads();
  return red[0] + red[1] + red[2] + red[3];
}
__device__ __forceinline__ float ln256(float y, float* red) {
  float mean = block_sum256(y, red) * (1.0f / 256.0f);
  float dv = y - mean;
  float var = block_sum256(dv * dv, red) * (1.0f / 256.0f);
  return dv * rsqrtf(var + 1e-5f);
}

// ---------------- encoder pointwise ----------------
__global__ __launch_bounds__(256) void k_encoder2(
    const float* __restrict__ Yc, const float* __restrict__ Yt,
    const float* __restrict__ numv,
    const float* __restrict__ Wn, const float* __restrict__ bn,
    const float* __restrict__ gc, const float* __restrict__ bec,
    const float* __restrict__ gn, const float* __restrict__ ben,
    const float* __restrict__ gt, const float* __restrict__ bet,
    const float* __restrict__ men, const float* __restrict__ met,
    const unsigned char* __restrict__ pad_b, const unsigned char* __restrict__ msk_b,
    const int* __restrict__ sem, float* __restrict__ x) {
  __shared__ float red[4];
  int token = blockIdx.x, d = threadIdx.x;
  int ispad = pad_b[token];
  float notpad = ispad ? 0.f : 1.f;
  int st = sem[token];
  int mk = msk_b[token];

  float yc = Yc[(size_t)token * 256 + d];
  float xv = (ln256(yc, red) * gc[d] + bec[d]) * notpad;

  {
    float yn = numv[token] * Wn[d] + bn[d];
    float lnv = ln256(yn, red) * gn[d] + ben[d];
    if (st == 0 && !ispad && !mk) xv += lnv;
    if (st == 0 && !ispad && mk)  xv += men[d];
  }
  if (st == 1 && !ispad && !mk) {
    float yt = Yt[(size_t)token * 256 + d];
    xv += ln256(yt, red) * gt[d] + bet[d];
  }
  if (st == 1 && !ispad && mk) xv += met[d];
  x[(size_t)token * 256 + d] = xv;
}

// ---------------- LN kernels ----------------
__global__ __launch_bounds__(256) void k_ln_bf(const float* __restrict__ xin,
                                               const float* __restrict__ g,
                                               const float* __restrict__ b,
                                               unsigned short* __restrict__ out) {
  __shared__ float red[4];
  int token = blockIdx.x, d = threadIdx.x;
  float v = xin[(size_t)token * 256 + d];
  out[(size_t)token * 256 + d] = f32_to_bf16(ln256(v, red) * g[d] + b[d]);
}

__global__ __launch_bounds__(256) void k_ln_add_bf(float* __restrict__ x,
                                                   const float* __restrict__ p0,
                                                   const float* __restrict__ p1,
                                                   const float* __restrict__ g,
                                                   const float* __restrict__ b,
                                                   unsigned short* __restrict__ out) {
  __shared__ float red[4];
  int token = blockIdx.x, d = threadIdx.x;
  size_t i = (size_t)token * 256 + d;
  float v = x[i] + p0[i] + p1[i];
  x[i] = v;
  out[i] = f32_to_bf16(ln256(v, red) * g[d] + b[d]);
}

__global__ __launch_bounds__(256) void k_ln_out_add(const float* __restrict__ xin,
                                                    const float* __restrict__ p0,
                                                    const float* __restrict__ p1,
                                                    const float* __restrict__ g,
                                                    const float* __restrict__ b,
                                                    void* __restrict__ out,
                                                    const int* __restrict__ flags) {
  __shared__ float red[4];
  int token = blockIdx.x, d = threadIdx.x;
  size_t idx = (size_t)token * 256 + d;
  float v = xin[idx] + p0[idx] + p1[idx];
  float o = ln256(v, red) * g[d] + b[d];
  if (flags[0]) ((unsigned short*)out)[idx] = f32_to_bf16(o);
  else ((float*)out)[idx] = o;
}

// ---------------- bf16 MFMA GEMM ----------------
__device__ __forceinline__ float gelu_tanh(float v) {
  const float c = 0.7978845608028654f;
  float t = tanhf(c * (v + 0.044715f * v * v * v));
  return 0.5f * v * (1.f + t);
}

template <int BM, int BN, int ACT, int OUT, int KS>
__global__ __launch_bounds__(256) void k_gemm_bf(
    const unsigned short* __restrict__ A, const unsigned short* __restrict__ Bt,
    const float* __restrict__ bias, void* __restrict__ Cv,
    unsigned short* __restrict__ VTp,
    int M, int N, int K) {
  __shared__ __align__(16) unsigned short As[BM][40];
  __shared__ __align__(16) unsigned short Bs[BN][40];
  constexpr int FI = BM / 32, FJ = BN / 32;
  int tid = threadIdx.x, wave = tid >> 6, lane = tid & 63;
  int g = lane >> 4, c = lane & 15;
  int wr = wave >> 1, wc = wave & 1;
  int bm = blockIdx.y * BM, bn = blockIdx.x * BN;
  int kz = (KS > 1) ? blockIdx.z : 0;
  f32x4 acc[FI][FJ] = {};
  int sr = tid >> 2, ss = (tid & 3) * 8;
  int kbeg = kz * (K / KS), kend = kbeg + K / KS;

  for (int k0 = kbeg; k0 < kend; k0 += 32) {
    __syncthreads();
#pragma unroll
    for (int rr = 0; rr < BM; rr += 64)
      *(short8*)&As[rr + sr][ss] = *(const short8*)&A[(size_t)(bm + rr + sr) * K + k0 + ss];
#pragma unroll
    for (int rr = 0; rr < BN; rr += 64)
      *(short8*)&Bs[rr + sr][ss] = *(const short8*)&Bt[(size_t)(bn + rr + sr) * K + k0 + ss];
    __syncthreads();
    short8 af[FI], bf[FJ];
#pragma unroll
    for (int i = 0; i < FI; i++) af[i] = *(short8*)&As[wr * (BM / 2) + i * 16 + c][g * 8];
#pragma unroll
    for (int j = 0; j < FJ; j++) bf[j] = *(short8*)&Bs[wc * (BN / 2) + j * 16 + c][g * 8];
#pragma unroll
    for (int i = 0; i < FI; i++)
#pragma unroll
      for (int j = 0; j < FJ; j++)
        acc[i][j] = __builtin_amdgcn_mfma_f32_16x16x32_bf16(af[i], bf[j], acc[i][j], 0, 0, 0);
  }

#pragma unroll
  for (int i = 0; i < FI; i++)
#pragma unroll
    for (int j = 0; j < FJ; j++) {
      int col = bn + wc * (BN / 2) + j * 16 + c;
      int row0 = bm + wr * (BM / 2) + i * 16 + g * 4;
      bool dovt = false;
      if (OUT == 2) {
        int ll = col / 768, cm = col - ll * 768;
        if (cm >= 512) {
          dovt = true;
          short4v pk;
#pragma unroll
          for (int r = 0; r < 4; r++) pk[r] = (short)f32_to_bf16(acc[i][j][r]);
          int bb = row0 >> 10, hh = (cm - 512) >> 5, dd = cm & 31;
          *(short4v*)&VTp[(size_t)(((bb * 4 + ll) * 8 + hh) * 32 + dd) * 1024 + (row0 & 1023)] = pk;
        }
      }
      if (!dovt) {
#pragma unroll
        for (int r = 0; r < 4; r++) {
          float v = acc[i][j][r];
          if (bias && kz == 0) v += bias[col];
          if (ACT) v = gelu_tanh(v);
          size_t idx = (size_t)(row0 + r) * N + col;
          if (OUT == 0) ((float*)Cv)[(size_t)kz * M * N + idx] = v;
          else ((unsigned short*)Cv)[idx] = f32_to_bf16(v);
        }
      }
    }
}

// ---------------- barrier-free swapped-QK MFMA masked flash attention ----------------
// 16 q-rows per 1-wave block; grid 4096: bid = qi*64 + h*8 + z, z=(b,l).
// Swapped QK^T: D = mfma(Kfrag, Qfrag) -> lane(g,c): P[key=16t+4g+r][q=q0+c]
// => packed b64 P writes, lane-local ls, exp2 with log2e folded into Q scale.
__global__ __launch_bounds__(64, 4) void k_attn2(
    const unsigned short* __restrict__ QKVb, const unsigned short* __restrict__ W3m,
    const unsigned short* __restrict__ VT, unsigned short* __restrict__ Ocat) {
  __shared__ __align__(16) unsigned short Pl[16][72];
  int bid = blockIdx.x;
  int z = bid & 7, h = (bid >> 3) & 7, qi = bid >> 6;
  int b = z >> 2, l = z & 3;
  int lane = threadIdx.x;
  int g = lane >> 4, c = lane & 15;
  int q0 = qi * 16;
  size_t tokbase = (size_t)b * SEQ;
  int qcol = l * 768 + h * 32;
  int kcol = qcol + 256;
  const unsigned short* vbase = VT + (size_t)(z * 8 + h) * 32 * 1024;
  // mask word: W3m[(z*1024+q0+c)*64 + kc*4 + g]
  const unsigned short* mbase = W3m + (size_t)(z * 1024 + q0 + c) * 64 + g;

  // Q fragment (B-layout), scale = 1/sqrt(32) * log2(e)
  short8 qf;
  {
    short8 qraw = *(const short8*)&QKVb[(tokbase + q0 + c) * 3072 + qcol + g * 8];
    const float sc = 0.25503487f;
#pragma unroll
    for (int j = 0; j < 8; j++)
      qf[j] = (short)f32_to_bf16(bf2f((unsigned short)qraw[j]) * sc);
  }

  f32x4 zero = {0.f, 0.f, 0.f, 0.f};
  f32x4 oacc0 = zero, oacc1 = zero;
  float ls = 0.f;   // partial sum for q = q0 + c over this lane's keys

  for (int kc = 0; kc < 16; kc++) {
    int kb0 = kc * 64;
    short8 kf[4];
#pragma unroll
    for (int t = 0; t < 4; t++)
      kf[t] = *(const short8*)&QKVb[(tokbase + kb0 + t * 16 + c) * 3072 + kcol + g * 8];
    unsigned mw = mbase[kc * 4];

    // QK^T (swapped): 4 MFMAs
    f32x4 sa[4];
    __builtin_amdgcn_s_setprio(1);
#pragma unroll
    for (int t = 0; t < 4; t++)
      sa[t] = __builtin_amdgcn_mfma_f32_16x16x32_bf16(kf[t], qf, zero, 0, 0, 0);
    __builtin_amdgcn_s_setprio(0);

    // mask + exp2 + packed P write (keys 16t+4g+0..3 for q=q0+c)
#pragma unroll
    for (int t = 0; t < 4; t++) {
      float pv[4];
#pragma unroll
      for (int r = 0; r < 4; r++) {
        float p = __builtin_amdgcn_exp2f(sa[t][r]);
        int ok = (mw >> (4 * t + r)) & 1;
        pv[r] = ok ? p : 0.f;
      }
      ls += (pv[0] + pv[1]) + (pv[2] + pv[3]);
      uint2 w2;
      w2.x = pk2bf(pv[0], pv[1]);
      w2.y = pk2bf(pv[2], pv[3]);
      *(uint2*)&Pl[c][t * 16 + g * 4] = w2;
    }

    // PV: O[16q][32d] += P[16][64] @ V[64][32]
#pragma unroll
    for (int k2 = 0; k2 < 2; k2++) {
      short8 pa = *(short8*)&Pl[c][k2 * 32 + g * 8];
      short8 v0 = *(const short8*)&vbase[(size_t)c * 1024 + kb0 + k2 * 32 + g * 8];
      short8 v1 = *(const short8*)&vbase[(size_t)(c + 16) * 1024 + kb0 + k2 * 32 + g * 8];
      __builtin_amdgcn_s_setprio(1);
      oacc0 = __builtin_amdgcn_mfma_f32_16x16x32_bf16(pa, v0, oacc0, 0, 0, 0);
      oacc1 = __builtin_amdgcn_mfma_f32_16x16x32_bf16(pa, v1, oacc1, 0, 0, 0);
      __builtin_amdgcn_s_setprio(0);
    }
  }

  // ls total per q=c: reduce over g-groups
  ls += __shfl_xor(ls, 16);
  ls += __shfl_xor(ls, 32);
  // per-output-row q = 4g+r: fetch ls from lane 4g+r, normalize, store
#pragma unroll
  for (int r = 0; r < 4; r++) {
    float lsr = __shfl(ls, g * 4 + r);
    float inv = (lsr > 0.f) ? (1.f / lsr) : 0.f;
    size_t row = tokbase + q0 + g * 4 + r;
    unsigned short* op = &Ocat[row * 1024 + l * 256 + h * 32];
    op[c] = f32_to_bf16(oacc0[r] * inv);
    op[c + 16] = f32_to_bf16(oacc1[r] * inv);
  }
}

// ---------------- host ----------------
extern "C" void kernel_launch(void* const* d_in, const int* in_sizes, int n_in,
                              void* d_out, int out_size, void* d_ws, size_t ws_size,
                              hipStream_t stream) {
  (void)n_in; (void)out_size; (void)ws_size;
  char* wsb = (char*)d_ws;
  int* flags = (int*)wsb;
  unsigned char* pad_b = (unsigned char*)(wsb + 256);
  unsigned char* msk_b = (unsigned char*)(wsb + 256 + 2048);
  float* fbase = (float*)(wsb + 8192);
  size_t fo = 0;
  auto alloc = [&](size_t n) { float* p = fbase + fo; fo += (n + 63) & ~(size_t)63; return p; };

  // f32 params
  float* bc = alloc(256);
  float* Wn = alloc(256);    float* bn = alloc(256);
  float* bt = alloc(256);
  float* gc = alloc(256);    float* bec = alloc(256);
  float* gn = alloc(256);    float* ben = alloc(256);
  float* gt = alloc(256);    float* bet = alloc(256);
  float* men = alloc(256);   float* met = alloc(256);
  float* l1g = alloc(512);   float* l1b = alloc(512);
  float* l2g = alloc(512);   float* l2b = alloc(512);
  float* b1c = alloc(2048);  float* b2c = alloc(512);
  float* goc = alloc(256);   float* beo = alloc(256);
  float* numv = alloc(2048);
  float* x = alloc(524288);
  // bf16 / u16 buffers
  unsigned short* W3m   = (unsigned short*)alloc(262144);  // 1 MB mask words
  unsigned short* h     = (unsigned short*)alloc(262144);
  unsigned short* WqkvT = (unsigned short*)alloc(786432);
  unsigned short* WoT   = (unsigned short*)alloc(262144);
  unsigned short* W1T   = (unsigned short*)alloc(262144);
  unsigned short* W2T   = (unsigned short*)alloc(262144);
  unsigned short* WcT   = (unsigned short*)alloc(49152);
  unsigned short* WtT   = (unsigned short*)alloc(49152);
  unsigned short* colvb = (unsigned short*)alloc(393216);
  unsigned short* textvb= (unsigned short*)alloc(393216);
  unsigned short* QKVb  = (unsigned short*)alloc(3145728);
  unsigned short* Ocat  = (unsigned short*)alloc(1048576);
  float* VTf            = alloc(1048576);
  unsigned short* VT    = (unsigned short*)VTf;
  float* p0 = VTf;                 // aliases: Yc / split-K partial 0
  float* p1 = VTf + 524288;        // aliases: Yt / split-K partial 1
  unsigned short* fbuf = QKVb;

  k_detect<<<1, 64, 0, stream>>>(d_in[7], d_in[6], flags);
  k_convert_bools<<<8, 256, 0, stream>>>(d_in[4], d_in[6], pad_b, msk_b, flags);

  ConvArgs ca;
  const int idxs[21] = {11, 12, 13, 15, 16, 17, 18, 19, 20, 21, 22, 23,
                        28, 29, 30, 31, 33, 35, 36, 37, 8};
  float* dsts[21] = {bc, Wn, bn, bt, gc, bec, gn, ben, gt, bet, men, met,
                     l1g, l1b, l2g, l2b, b1c, b2c, goc, beo, numv};
  for (int t = 0; t < 21; t++) {
    ca.e[t].src = d_in[idxs[t]];
    ca.e[t].dst = dsts[t];
    ca.e[t].n = in_sizes[idxs[t]];
  }
  k_convert_many<<<dim3(8, 21), 256, 0, stream>>>(ca, flags);
  k_conv_bf<<<768, 256, 0, stream>>>(d_in[7], colvb, 786432, flags);
  k_conv_bf<<<768, 256, 0, stream>>>(d_in[9], textvb, 786432, flags);

  TArgs ta;
  int ne = 0;
  for (int i = 0; i < 2; i++)
    for (int l = 0; l < 4; l++)
      for (int w = 0; w < 3; w++) {
        ta.e[ne].src = d_in[24 + w];
        ta.e[ne].soff = (i * 4 + l) * 65536;
        ta.e[ne].dst = WqkvT + (size_t)i * 786432 + (size_t)(l * 768 + w * 256) * 256;
        ta.e[ne].K = 256; ta.e[ne].N = 256; ta.e[ne].pitch = 256;
        ne++;
      }
  for (int i = 0; i < 2; i++)
    for (int l = 0; l < 4; l++) {
      ta.e[ne].src = d_in[27];
      ta.e[ne].soff = (i * 4 + l) * 65536;
      ta.e[ne].dst = WoT + (size_t)i * 262144 + l * 256;
      ta.e[ne].K = 256; ta.e[ne].N = 256; ta.e[ne].pitch = 1024;
      ne++;
    }
  for (int i = 0; i < 2; i++) {
    ta.e[ne].src = d_in[32];
    ta.e[ne].soff = i * 262144;
    ta.e[ne].dst = W1T + (size_t)i * 262144;
    ta.e[ne].K = 256; ta.e[ne].N = 1024; ta.e[ne].pitch = 256;
    ne++;
  }
  for (int i = 0; i < 2; i++) {
    ta.e[ne].src = d_in[34];
    ta.e[ne].soff = i * 262144;
    ta.e[ne].dst = W2T + (size_t)i * 262144;
    ta.e[ne].K = 1024; ta.e[ne].N = 256; ta.e[ne].pitch = 1024;
    ne++;
  }
  ta.e[ne].src = d_in[10]; ta.e[ne].soff = 0; ta.e[ne].dst = WcT;
  ta.e[ne].K = 384; ta.e[ne].N = 256; ta.e[ne].pitch = 384; ne++;
  ta.e[ne].src = d_in[14]; ta.e[ne].soff = 0; ta.e[ne].dst = WtT;
  ta.e[ne].K = 384; ta.e[ne].N = 256; ta.e[ne].pitch = 384; ne++;
  k_conv_T<<<dim3(256, 38), 256, 0, stream>>>(ta, flags);

  k_masks3<<<dim3(16, 64, 8), 64, 0, stream>>>(
      (const int*)d_in[0], (const int*)d_in[1], (const int*)d_in[2],
      (const int*)d_in[3], pad_b, W3m);

  // encoder
  k_gemm_bf<128, 128, 0, 0, 1><<<dim3(2, 16), 256, 0, stream>>>(
      colvb, WcT, bc, p0, nullptr, 2048, 256, 384);
  k_gemm_bf<128, 128, 0, 0, 1><<<dim3(2, 16), 256, 0, stream>>>(
      textvb, WtT, bt, p1, nullptr, 2048, 256, 384);
  k_encoder2<<<2048, 256, 0, stream>>>(p0, p1, numv, Wn, bn, gc, bec, gn, ben,
                                       gt, bet, men, met, pad_b, msk_b,
                                       (const int*)d_in[5], x);

  k_ln_bf<<<2048, 256, 0, stream>>>(x, l1g, l1b, h);
  for (int i = 0; i < 2; i++) {
    k_gemm_bf<128, 128, 0, 2, 1><<<dim3(24, 16), 256, 0, stream>>>(
        h, WqkvT + (size_t)i * 786432, nullptr, QKVb, VT, 2048, 3072, 256);
    k_attn2<<<4096, 64, 0, stream>>>(QKVb, W3m, VT, Ocat);
    k_gemm_bf<64, 64, 0, 0, 2><<<dim3(4, 32, 2), 256, 0, stream>>>(
        Ocat, WoT + (size_t)i * 262144, nullptr, p0, nullptr, 2048, 256, 1024);
    k_ln_add_bf<<<2048, 256, 0, stream>>>(x, p0, p1, l2g + i * 256, l2b + i * 256, h);
    k_gemm_bf<128, 64, 1, 1, 1><<<dim3(16, 16), 256, 0, stream>>>(
        h, W1T + (size_t)i * 262144, b1c + (size_t)i * 1024, fbuf, nullptr, 2048, 1024, 256);
    k_gemm_bf<64, 64, 0, 0, 2><<<dim3(4, 32, 2), 256, 0, stream>>>(
        fbuf, W2T + (size_t)i * 262144, b2c + (size_t)i * 256, p0, nullptr, 2048, 256, 1024);
    if (i == 0)
      k_ln_add_bf<<<2048, 256, 0, stream>>>(x, p0, p1, l1g + 256, l1b + 256, h);
    else
      k_ln_out_add<<<2048, 256, 0, stream>>>(x, p0, p1, goc, beo, d_out, flags);
  }
}

// Round 7
// 286.475 us; speedup vs baseline: 1.1756x; 1.1756x over previous
//
#include <hip/hip_runtime.h>
#include <stdint.h>

#define TOKS 2048
#define SEQ 1024

typedef __attribute__((ext_vector_type(8))) short short8;
typedef __attribute__((ext_vector_type(4))) short short4v;
typedef __attribute__((ext_vector_type(4))) float f32x4;

// ---------------- dtype helpers ----------------
__device__ __forceinline__ float loadf(const void* p, size_t i, int isbf16) {
  if (isbf16) {
    unsigned short u = ((const unsigned short*)p)[i];
    return __uint_as_float(((unsigned)u) << 16);
  }
  return ((const float*)p)[i];
}
__device__ __forceinline__ unsigned short f32_to_bf16(float f) {
  unsigned u = __float_as_uint(f);
  unsigned r = u + 0x7FFFu + ((u >> 16) & 1u);
  return (unsigned short)(r >> 16);
}
__device__ __forceinline__ float bf2f(unsigned short u) {
  return __uint_as_float(((unsigned)u) << 16);
}
__device__ __forceinline__ unsigned pk2bf(float a, float b) {
  return ((unsigned)f32_to_bf16(b) << 16) | (unsigned)f32_to_bf16(a);
}

// ---------------- detection ----------------
__global__ void k_detect(const void* fs, const void* bs, int* flags) {
  int lane = threadIdx.x;
  int bad = 0;
  for (int i = lane; i < 256; i += 64) {
    unsigned short u = ((const unsigned short*)fs)[i];
    float v = __uint_as_float(((unsigned)u) << 16);
    if (!(fabsf(v) <= 100.f)) bad = 1;
  }
  int big = 0;
  for (int i = lane; i < 512; i += 64) {
    if (((const unsigned*)bs)[i] > 1u) big = 1;
  }
#pragma unroll
  for (int off = 32; off; off >>= 1) {
    bad |= __shfl_xor(bad, off);
    big |= __shfl_xor(big, off);
  }
  if (lane == 0) { flags[0] = bad ? 0 : 1; flags[1] = big ? 1 : 0; }
}

// ---------------- canonicalization ----------------
struct ConvEntry { const void* src; float* dst; int n; };
struct ConvArgs { ConvEntry e[21]; };

__global__ void k_convert_many(ConvArgs ca, const int* __restrict__ flags) {
  int isbf = flags[0];
  ConvEntry E = ca.e[blockIdx.y];
  for (int i = blockIdx.x * 256 + threadIdx.x; i < E.n; i += gridDim.x * 256)
    E.dst[i] = loadf(E.src, (size_t)i, isbf);
}

__global__ void k_conv_bf(const void* src, unsigned short* __restrict__ dst,
                          int n, const int* __restrict__ flags) {
  int isbf = flags[0];
  int i = (blockIdx.x * 256 + threadIdx.x) * 4;
  if (i < n) {
#pragma unroll
    for (int j = 0; j < 4; j++) dst[i + j] = f32_to_bf16(loadf(src, i + j, isbf));
  }
}

__global__ void k_convert_bools(const void* pad, const void* msk,
                                unsigned char* pb, unsigned char* mb,
                                const int* __restrict__ flags) {
  int isb = flags[1];
  int i = blockIdx.x * 256 + threadIdx.x;
  if (i < TOKS) {
    if (isb) {
      pb[i] = ((const unsigned char*)pad)[i] ? 1 : 0;
      mb[i] = ((const unsigned char*)msk)[i] ? 1 : 0;
    } else {
      pb[i] = (((const int*)pad)[i] != 0) ? 1 : 0;
      mb[i] = (((const int*)msk)[i] != 0) ? 1 : 0;
    }
  }
}

// ---------------- transposed bf16 weight conversion ----------------
struct TEntry { const void* src; unsigned short* dst; int soff, K, N, pitch; };
struct TArgs { TEntry e[38]; };

__global__ __launch_bounds__(256) void k_conv_T(TArgs ta, const int* __restrict__ flags) {
  int isbf = flags[0];
  TEntry E = ta.e[blockIdx.y];
  int ktiles = E.K >> 5, ntiles = E.N >> 5;
  if ((int)blockIdx.x >= ktiles * ntiles) return;
  int tk = blockIdx.x % ktiles, tn = blockIdx.x / ktiles;
  __shared__ float t[32][33];
  int tx = threadIdx.x & 31, ty = threadIdx.x >> 5;
#pragma unroll
  for (int s = 0; s < 4; s++) {
    int k = tk * 32 + ty + s * 8, n = tn * 32 + tx;
    t[ty + s * 8][tx] = loadf(E.src, (size_t)E.soff + (size_t)k * E.N + n, isbf);
  }
  __syncthreads();
#pragma unroll
  for (int s = 0; s < 4; s++) {
    int n = tn * 32 + ty + s * 8, k = tk * 32 + tx;
    E.dst[(size_t)n * E.pitch + k] = f32_to_bf16(t[tx][ty + s * 8]);
  }
}

// ---------------- mask words (transposed for swapped-QK attn) ----------------
// W3m[((z*1024 + q)*16 + kc)*4 + g] : u16, bit (4t+r) = mask(q, key=kc*64+16t+4g+r)
__global__ __launch_bounds__(64) void k_masks3(
    const int* __restrict__ node, const int* __restrict__ f2p,
    const int* __restrict__ colid, const int* __restrict__ tabid,
    const unsigned char* __restrict__ pad_b, unsigned short* __restrict__ W3m) {
  int kc = blockIdx.x, qb = blockIdx.y, z = blockIdx.z;
  int b = z >> 2, l = z & 3;
  int base = b * SEQ;
  int tid = threadIdx.x;
  __shared__ int kn[64], kcl[64], ktb[64], kpd[64], kf2[64][8];
  __shared__ int qn[16], qcl[16], qtb[16], qpd[16], qf2[16][8];

  int kkey = base + kc * 64 + tid;
  kn[tid] = node[kkey];
  kcl[tid] = colid[kkey];
  ktb[tid] = tabid[kkey];
  kpd[tid] = pad_b[kkey] ? 0 : 1;
  if (l == 1) {
#pragma unroll
    for (int j = 0; j < 8; j++) kf2[tid][j] = f2p[(size_t)kkey * 8 + j];
  }
  if (tid < 16) {
    int qq = base + qb * 16 + tid;
    qn[tid] = node[qq]; qcl[tid] = colid[qq]; qtb[tid] = tabid[qq];
    qpd[tid] = pad_b[qq] ? 0 : 1;
  }
  if (l == 0) {
#pragma unroll
    for (int s = 0; s < 2; s++) {
      int i = tid + s * 64;
      qf2[i >> 3][i & 7] = f2p[(size_t)(base + qb * 16 + (i >> 3)) * 8 + (i & 7)];
    }
  }
  __syncthreads();

  int q = tid & 15, g = tid >> 4;
  unsigned w = 0;
#pragma unroll
  for (int t = 0; t < 4; t++) {
#pragma unroll
    for (int r = 0; r < 4; r++) {
      int kl = t * 16 + g * 4 + r;
      int sel;
      if (l == 0) {
        int nk = kn[kl];
        sel = (qn[q] == nk);
#pragma unroll
        for (int j = 0; j < 8; j++) sel |= (qf2[q][j] == nk);
      } else if (l == 1) {
        int n = qn[q];
        sel = (n == kf2[kl][0]) | (n == kf2[kl][1]) | (n == kf2[kl][2]) | (n == kf2[kl][3]) |
              (n == kf2[kl][4]) | (n == kf2[kl][5]) | (n == kf2[kl][6]) | (n == kf2[kl][7]);
      } else if (l == 2) {
        sel = (qcl[q] == kcl[kl]) & (qtb[q] == ktb[kl]);
      } else {
        sel = 1;
      }
      w |= (unsigned)(sel & qpd[q] & kpd[kl]) << (4 * t + r);
    }
  }
  W3m[((size_t)(z * 1024 + qb * 16 + q) * 16 + kc) * 4 + g] = (unsigned short)w;
}

// ---------------- block reductions / LN ----------------
__device__ __forceinline__ float block_sum256(float v, float* red) {
#pragma unroll
  for (int off = 32; off; off >>= 1) v += __shfl_xor(v, off);
  int w = threadIdx.x >> 6;
  __syncthreads();
  if ((threadIdx.x & 63) == 0) red[w] = v;
  __syncthreads();
  return red[0] + red[1] + red[2] + red[3];
}
__device__ __forceinline__ float ln256(float y, float* red) {
  float mean = block_sum256(y, red) * (1.0f / 256.0f);
  float dv = y - mean;
  float var = block_sum256(dv * dv, red) * (1.0f / 256.0f);
  return dv * rsqrtf(var + 1e-5f);
}

// ---------------- encoder pointwise ----------------
__global__ __launch_bounds__(256) void k_encoder2(
    const float* __restrict__ Yc, const float* __restrict__ Yt,
    const float* __restrict__ numv,
    const float* __restrict__ Wn, const float* __restrict__ bn,
    const float* __restrict__ gc, const float* __restrict__ bec,
    const float* __restrict__ gn, const float* __restrict__ ben,
    const float* __restrict__ gt, const float* __restrict__ bet,
    const float* __restrict__ men, const float* __restrict__ met,
    const unsigned char* __restrict__ pad_b, const unsigned char* __restrict__ msk_b,
    const int* __restrict__ sem, float* __restrict__ x) {
  __shared__ float red[4];
  int token = blockIdx.x, d = threadIdx.x;
  int ispad = pad_b[token];
  float notpad = ispad ? 0.f : 1.f;
  int st = sem[token];
  int mk = msk_b[token];

  float yc = Yc[(size_t)token * 256 + d];
  float xv = (ln256(yc, red) * gc[d] + bec[d]) * notpad;

  {
    float yn = numv[token] * Wn[d] + bn[d];
    float lnv = ln256(yn, red) * gn[d] + ben[d];
    if (st == 0 && !ispad && !mk) xv += lnv;
    if (st == 0 && !ispad && mk)  xv += men[d];
  }
  if (st == 1 && !ispad && !mk) {
    float yt = Yt[(size_t)token * 256 + d];
    xv += ln256(yt, red) * gt[d] + bet[d];
  }
  if (st == 1 && !ispad && mk) xv += met[d];
  x[(size_t)token * 256 + d] = xv;
}

// ---------------- LN kernels ----------------
__global__ __launch_bounds__(256) void k_ln_bf(const float* __restrict__ xin,
                                               const float* __restrict__ g,
                                               const float* __restrict__ b,
                                               unsigned short* __restrict__ out) {
  __shared__ float red[4];
  int token = blockIdx.x, d = threadIdx.x;
  float v = xin[(size_t)token * 256 + d];
  out[(size_t)token * 256 + d] = f32_to_bf16(ln256(v, red) * g[d] + b[d]);
}

__global__ __launch_bounds__(256) void k_ln_add_bf(float* __restrict__ x,
                                                   const float* __restrict__ p0,
                                                   const float* __restrict__ p1,
                                                   const float* __restrict__ g,
                                                   const float* __restrict__ b,
                                                   unsigned short* __restrict__ out) {
  __shared__ float red[4];
  int token = blockIdx.x, d = threadIdx.x;
  size_t i = (size_t)token * 256 + d;
  float v = x[i] + p0[i] + p1[i];
  x[i] = v;
  out[i] = f32_to_bf16(ln256(v, red) * g[d] + b[d]);
}

__global__ __launch_bounds__(256) void k_ln_out_add(const float* __restrict__ xin,
                                                    const float* __restrict__ p0,
                                                    const float* __restrict__ p1,
                                                    const float* __restrict__ g,
                                                    const float* __restrict__ b,
                                                    void* __restrict__ out,
                                                    const int* __restrict__ flags) {
  __shared__ float red[4];
  int token = blockIdx.x, d = threadIdx.x;
  size_t idx = (size_t)token * 256 + d;
  float v = xin[idx] + p0[idx] + p1[idx];
  float o = ln256(v, red) * g[d] + b[d];
  if (flags[0]) ((unsigned short*)out)[idx] = f32_to_bf16(o);
  else ((float*)out)[idx] = o;
}

// ---------------- bf16 MFMA GEMM ----------------
__device__ __forceinline__ float gelu_tanh(float v) {
  const float c = 0.7978845608028654f;
  float t = tanhf(c * (v + 0.044715f * v * v * v));
  return 0.5f * v * (1.f + t);
}

template <int BM, int BN, int ACT, int OUT, int KS>
__global__ __launch_bounds__(256) void k_gemm_bf(
    const unsigned short* __restrict__ A, const unsigned short* __restrict__ Bt,
    const float* __restrict__ bias, void* __restrict__ Cv,
    unsigned short* __restrict__ VTp,
    int M, int N, int K) {
  __shared__ __align__(16) unsigned short As[BM][40];
  __shared__ __align__(16) unsigned short Bs[BN][40];
  constexpr int FI = BM / 32, FJ = BN / 32;
  int tid = threadIdx.x, wave = tid >> 6, lane = tid & 63;
  int g = lane >> 4, c = lane & 15;
  int wr = wave >> 1, wc = wave & 1;
  int bm = blockIdx.y * BM, bn = blockIdx.x * BN;
  int kz = (KS > 1) ? blockIdx.z : 0;
  f32x4 acc[FI][FJ] = {};
  int sr = tid >> 2, ss = (tid & 3) * 8;
  int kbeg = kz * (K / KS), kend = kbeg + K / KS;

  for (int k0 = kbeg; k0 < kend; k0 += 32) {
    __syncthreads();
#pragma unroll
    for (int rr = 0; rr < BM; rr += 64)
      *(short8*)&As[rr + sr][ss] = *(const short8*)&A[(size_t)(bm + rr + sr) * K + k0 + ss];
#pragma unroll
    for (int rr = 0; rr < BN; rr += 64)
      *(short8*)&Bs[rr + sr][ss] = *(const short8*)&Bt[(size_t)(bn + rr + sr) * K + k0 + ss];
    __syncthreads();
    short8 af[FI], bf[FJ];
#pragma unroll
    for (int i = 0; i < FI; i++) af[i] = *(short8*)&As[wr * (BM / 2) + i * 16 + c][g * 8];
#pragma unroll
    for (int j = 0; j < FJ; j++) bf[j] = *(short8*)&Bs[wc * (BN / 2) + j * 16 + c][g * 8];
#pragma unroll
    for (int i = 0; i < FI; i++)
#pragma unroll
      for (int j = 0; j < FJ; j++)
        acc[i][j] = __builtin_amdgcn_mfma_f32_16x16x32_bf16(af[i], bf[j], acc[i][j], 0, 0, 0);
  }

#pragma unroll
  for (int i = 0; i < FI; i++)
#pragma unroll
    for (int j = 0; j < FJ; j++) {
      int col = bn + wc * (BN / 2) + j * 16 + c;
      int row0 = bm + wr * (BM / 2) + i * 16 + g * 4;
      bool dovt = false;
      if (OUT == 2) {
        int ll = col / 768, cm = col - ll * 768;
        if (cm >= 512) {
          dovt = true;
          short4v pk;
#pragma unroll
          for (int r = 0; r < 4; r++) pk[r] = (short)f32_to_bf16(acc[i][j][r]);
          int bb = row0 >> 10, hh = (cm - 512) >> 5, dd = cm & 31;
          *(short4v*)&VTp[(size_t)(((bb * 4 + ll) * 8 + hh) * 32 + dd) * 1024 + (row0 & 1023)] = pk;
        }
      }
      if (!dovt) {
#pragma unroll
        for (int r = 0; r < 4; r++) {
          float v = acc[i][j][r];
          if (bias && kz == 0) v += bias[col];
          if (ACT) v = gelu_tanh(v);
          size_t idx = (size_t)(row0 + r) * N + col;
          if (OUT == 0) ((float*)Cv)[(size_t)kz * M * N + idx] = v;
          else ((unsigned short*)Cv)[idx] = f32_to_bf16(v);
        }
      }
    }
}

// ---------------- 4-wave split-K swapped-QK MFMA masked flash attention ----------------
// Block: 256 thr = 4 waves, one (z,h,q-block-of-32). Wave w handles keys [w*256, w*256+256).
// grid 2048: bid = qi*64 + h*8 + z, z=(b,l) [XCD-local].
// Swapped QK^T: D = mfma(K,Q) -> lane(g,c): P[key=16t+4g+r][q=c] => packed b64 P writes,
// lane-local ls, exp2 with log2e folded into Q scale. One barrier; wave 0 combines.
__global__ __launch_bounds__(256) void k_attn3(
    const unsigned short* __restrict__ QKVb, const unsigned short* __restrict__ W3m,
    const unsigned short* __restrict__ VT, unsigned short* __restrict__ Ocat) {
  __shared__ __align__(16) unsigned short Pl[4][32][72];  // per-wave P; reused as f32 partial O
  __shared__ float lsv[4][32];
  int bid = blockIdx.x;
  int z = bid & 7, h = (bid >> 3) & 7, qi = bid >> 6;
  int b = z >> 2, l = z & 3;
  int tid = threadIdx.x;
  int wave = tid >> 6, lane = tid & 63;
  int g = lane >> 4, c = lane & 15;
  int q0 = qi * 32;
  size_t tokbase = (size_t)b * SEQ;
  int qcol = l * 768 + h * 32;
  int kcol = qcol + 256;
  const unsigned short* vbase = VT + (size_t)(z * 8 + h) * 32 * 1024;

  // Q fragments (B-layout) for q = q0+c and q0+16+c; scale = 1/sqrt(32)*log2(e)
  short8 qf[2];
#pragma unroll
  for (int s = 0; s < 2; s++) {
    short8 qraw = *(const short8*)&QKVb[(tokbase + q0 + s * 16 + c) * 3072 + qcol + g * 8];
    const float sc = 0.25503487f;
#pragma unroll
    for (int j = 0; j < 8; j++)
      qf[s][j] = (short)f32_to_bf16(bf2f((unsigned short)qraw[j]) * sc);
  }

  f32x4 zero = {0.f, 0.f, 0.f, 0.f};
  f32x4 oacc[2][2];
  oacc[0][0] = zero; oacc[0][1] = zero; oacc[1][0] = zero; oacc[1][1] = zero;
  float ls[2] = {0.f, 0.f};

  for (int kc = wave * 4; kc < wave * 4 + 4; kc++) {
    int kb0 = kc * 64;
    short8 kf[4];
#pragma unroll
    for (int t = 0; t < 4; t++)
      kf[t] = *(const short8*)&QKVb[(tokbase + kb0 + t * 16 + c) * 3072 + kcol + g * 8];
    unsigned mw[2];
#pragma unroll
    for (int s = 0; s < 2; s++)
      mw[s] = W3m[(size_t)(z * 1024 + q0 + s * 16 + c) * 64 + kc * 4 + g];

#pragma unroll
    for (int s = 0; s < 2; s++) {
      f32x4 sa[4];
      __builtin_amdgcn_s_setprio(1);
#pragma unroll
      for (int t = 0; t < 4; t++)
        sa[t] = __builtin_amdgcn_mfma_f32_16x16x32_bf16(kf[t], qf[s], zero, 0, 0, 0);
      __builtin_amdgcn_s_setprio(0);
#pragma unroll
      for (int t = 0; t < 4; t++) {
        float pv[4];
#pragma unroll
        for (int r = 0; r < 4; r++) {
          float p = __builtin_amdgcn_exp2f(sa[t][r]);
          int ok = (mw[s] >> (4 * t + r)) & 1;
          pv[r] = ok ? p : 0.f;
        }
        ls[s] += (pv[0] + pv[1]) + (pv[2] + pv[3]);
        uint2 w2;
        w2.x = pk2bf(pv[0], pv[1]);
        w2.y = pk2bf(pv[2], pv[3]);
        *(uint2*)&Pl[wave][s * 16 + c][t * 16 + g * 4] = w2;
      }
    }

    // PV: O[32q][32d] += P[32q][64k] @ V[64k][32d]
#pragma unroll
    for (int k2 = 0; k2 < 2; k2++) {
      short8 v0 = *(const short8*)&vbase[(size_t)c * 1024 + kb0 + k2 * 32 + g * 8];
      short8 v1 = *(const short8*)&vbase[(size_t)(c + 16) * 1024 + kb0 + k2 * 32 + g * 8];
      __builtin_amdgcn_s_setprio(1);
#pragma unroll
      for (int s = 0; s < 2; s++) {
        short8 pa = *(short8*)&Pl[wave][s * 16 + c][k2 * 32 + g * 8];
        oacc[s][0] = __builtin_amdgcn_mfma_f32_16x16x32_bf16(pa, v0, oacc[s][0], 0, 0, 0);
        oacc[s][1] = __builtin_amdgcn_mfma_f32_16x16x32_bf16(pa, v1, oacc[s][1], 0, 0, 0);
      }
      __builtin_amdgcn_s_setprio(0);
    }
  }

  // reduce ls over g-groups (lane-local per q=c / q=c+16)
#pragma unroll
  for (int s = 0; s < 2; s++) {
    ls[s] += __shfl_xor(ls[s], 16);
    ls[s] += __shfl_xor(ls[s], 32);
  }
  // dump partials: O -> own Pl region (as f32 [32][33]), ls -> lsv
  {
    float* ob = (float*)&Pl[wave][0][0];
#pragma unroll
    for (int s = 0; s < 2; s++) {
      if (g == 0) lsv[wave][s * 16 + c] = ls[s];
#pragma unroll
      for (int r = 0; r < 4; r++) {
        ob[(s * 16 + g * 4 + r) * 33 + c] = oacc[s][0][r];
        ob[(s * 16 + g * 4 + r) * 33 + 16 + c] = oacc[s][1][r];
      }
    }
  }
  __syncthreads();
  if (wave == 0) {
#pragma unroll
    for (int s = 0; s < 2; s++) {
#pragma unroll
      for (int r = 0; r < 4; r++) {
        int ql = s * 16 + g * 4 + r;
        float lst = lsv[0][ql] + lsv[1][ql] + lsv[2][ql] + lsv[3][ql];
        float inv = (lst > 0.f) ? (1.f / lst) : 0.f;
        float o0 = 0.f, o1 = 0.f;
#pragma unroll
        for (int w = 0; w < 4; w++) {
          const float* ob = (const float*)&Pl[w][0][0];
          o0 += ob[ql * 33 + c];
          o1 += ob[ql * 33 + 16 + c];
        }
        size_t row = tokbase + q0 + ql;
        unsigned short* op = &Ocat[row * 1024 + l * 256 + h * 32];
        op[c] = f32_to_bf16(o0 * inv);
        op[c + 16] = f32_to_bf16(o1 * inv);
      }
    }
  }
}

// ---------------- host ----------------
extern "C" void kernel_launch(void* const* d_in, const int* in_sizes, int n_in,
                              void* d_out, int out_size, void* d_ws, size_t ws_size,
                              hipStream_t stream) {
  (void)n_in; (void)out_size; (void)ws_size;
  char* wsb = (char*)d_ws;
  int* flags = (int*)wsb;
  unsigned char* pad_b = (unsigned char*)(wsb + 256);
  unsigned char* msk_b = (unsigned char*)(wsb + 256 + 2048);
  float* fbase = (float*)(wsb + 8192);
  size_t fo = 0;
  auto alloc = [&](size_t n) { float* p = fbase + fo; fo += (n + 63) & ~(size_t)63; return p; };

  // f32 params
  float* bc = alloc(256);
  float* Wn = alloc(256);    float* bn = alloc(256);
  float* bt = alloc(256);
  float* gc = alloc(256);    float* bec = alloc(256);
  float* gn = alloc(256);    float* ben = alloc(256);
  float* gt = alloc(256);    float* bet = alloc(256);
  float* men = alloc(256);   float* met = alloc(256);
  float* l1g = alloc(512);   float* l1b = alloc(512);
  float* l2g = alloc(512);   float* l2b = alloc(512);
  float* b1c = alloc(2048);  float* b2c = alloc(512);
  float* goc = alloc(256);   float* beo = alloc(256);
  float* numv = alloc(2048);
  float* x = alloc(524288);
  // bf16 / u16 buffers
  unsigned short* W3m   = (unsigned short*)alloc(262144);
  unsigned short* h     = (unsigned short*)alloc(262144);
  unsigned short* WqkvT = (unsigned short*)alloc(786432);
  unsigned short* WoT   = (unsigned short*)alloc(262144);
  unsigned short* W1T   = (unsigned short*)alloc(262144);
  unsigned short* W2T   = (unsigned short*)alloc(262144);
  unsigned short* WcT   = (unsigned short*)alloc(49152);
  unsigned short* WtT   = (unsigned short*)alloc(49152);
  unsigned short* colvb = (unsigned short*)alloc(393216);
  unsigned short* textvb= (unsigned short*)alloc(393216);
  unsigned short* QKVb  = (unsigned short*)alloc(3145728);
  unsigned short* Ocat  = (unsigned short*)alloc(1048576);
  float* VTf            = alloc(1048576);
  unsigned short* VT    = (unsigned short*)VTf;
  float* p0 = VTf;                 // aliases: Yc / split-K partial 0
  float* p1 = VTf + 524288;        // aliases: Yt / split-K partial 1
  unsigned short* fbuf = QKVb;

  k_detect<<<1, 64, 0, stream>>>(d_in[7], d_in[6], flags);
  k_convert_bools<<<8, 256, 0, stream>>>(d_in[4], d_in[6], pad_b, msk_b, flags);

  ConvArgs ca;
  const int idxs[21] = {11, 12, 13, 15, 16, 17, 18, 19, 20, 21, 22, 23,
                        28, 29, 30, 31, 33, 35, 36, 37, 8};
  float* dsts[21] = {bc, Wn, bn, bt, gc, bec, gn, ben, gt, bet, men, met,
                     l1g, l1b, l2g, l2b, b1c, b2c, goc, beo, numv};
  for (int t = 0; t < 21; t++) {
    ca.e[t].src = d_in[idxs[t]];
    ca.e[t].dst = dsts[t];
    ca.e[t].n = in_sizes[idxs[t]];
  }
  k_convert_many<<<dim3(8, 21), 256, 0, stream>>>(ca, flags);
  k_conv_bf<<<768, 256, 0, stream>>>(d_in[7], colvb, 786432, flags);
  k_conv_bf<<<768, 256, 0, stream>>>(d_in[9], textvb, 786432, flags);

  TArgs ta;
  int ne = 0;
  for (int i = 0; i < 2; i++)
    for (int l = 0; l < 4; l++)
      for (int w = 0; w < 3; w++) {
        ta.e[ne].src = d_in[24 + w];
        ta.e[ne].soff = (i * 4 + l) * 65536;
        ta.e[ne].dst = WqkvT + (size_t)i * 786432 + (size_t)(l * 768 + w * 256) * 256;
        ta.e[ne].K = 256; ta.e[ne].N = 256; ta.e[ne].pitch = 256;
        ne++;
      }
  for (int i = 0; i < 2; i++)
    for (int l = 0; l < 4; l++) {
      ta.e[ne].src = d_in[27];
      ta.e[ne].soff = (i * 4 + l) * 65536;
      ta.e[ne].dst = WoT + (size_t)i * 262144 + l * 256;
      ta.e[ne].K = 256; ta.e[ne].N = 256; ta.e[ne].pitch = 1024;
      ne++;
    }
  for (int i = 0; i < 2; i++) {
    ta.e[ne].src = d_in[32];
    ta.e[ne].soff = i * 262144;
    ta.e[ne].dst = W1T + (size_t)i * 262144;
    ta.e[ne].K = 256; ta.e[ne].N = 1024; ta.e[ne].pitch = 256;
    ne++;
  }
  for (int i = 0; i < 2; i++) {
    ta.e[ne].src = d_in[34];
    ta.e[ne].soff = i * 262144;
    ta.e[ne].dst = W2T + (size_t)i * 262144;
    ta.e[ne].K = 1024; ta.e[ne].N = 256; ta.e[ne].pitch = 1024;
    ne++;
  }
  ta.e[ne].src = d_in[10]; ta.e[ne].soff = 0; ta.e[ne].dst = WcT;
  ta.e[ne].K = 384; ta.e[ne].N = 256; ta.e[ne].pitch = 384; ne++;
  ta.e[ne].src = d_in[14]; ta.e[ne].soff = 0; ta.e[ne].dst = WtT;
  ta.e[ne].K = 384; ta.e[ne].N = 256; ta.e[ne].pitch = 384; ne++;
  k_conv_T<<<dim3(256, 38), 256, 0, stream>>>(ta, flags);

  k_masks3<<<dim3(16, 64, 8), 64, 0, stream>>>(
      (const int*)d_in[0], (const int*)d_in[1], (const int*)d_in[2],
      (const int*)d_in[3], pad_b, W3m);

  // encoder
  k_gemm_bf<128, 128, 0, 0, 1><<<dim3(2, 16), 256, 0, stream>>>(
      colvb, WcT, bc, p0, nullptr, 2048, 256, 384);
  k_gemm_bf<128, 128, 0, 0, 1><<<dim3(2, 16), 256, 0, stream>>>(
      textvb, WtT, bt, p1, nullptr, 2048, 256, 384);
  k_encoder2<<<2048, 256, 0, stream>>>(p0, p1, numv, Wn, bn, gc, bec, gn, ben,
                                       gt, bet, men, met, pad_b, msk_b,
                                       (const int*)d_in[5], x);

  k_ln_bf<<<2048, 256, 0, stream>>>(x, l1g, l1b, h);
  for (int i = 0; i < 2; i++) {
    k_gemm_bf<128, 128, 0, 2, 1><<<dim3(24, 16), 256, 0, stream>>>(
        h, WqkvT + (size_t)i * 786432, nullptr, QKVb, VT, 2048, 3072, 256);
    k_attn3<<<2048, 256, 0, stream>>>(QKVb, W3m, VT, Ocat);
    k_gemm_bf<64, 64, 0, 0, 2><<<dim3(4, 32, 2), 256, 0, stream>>>(
        Ocat, WoT + (size_t)i * 262144, nullptr, p0, nullptr, 2048, 256, 1024);
    k_ln_add_bf<<<2048, 256, 0, stream>>>(x, p0, p1, l2g + i * 256, l2b + i * 256, h);
    k_gemm_bf<128, 64, 1, 1, 1><<<dim3(16, 16), 256, 0, stream>>>(
        h, W1T + (size_t)i * 262144, b1c + (size_t)i * 1024, fbuf, nullptr, 2048, 1024, 256);
    k_gemm_bf<64, 64, 0, 0, 2><<<dim3(4, 32, 2), 256, 0, stream>>>(
        fbuf, W2T + (size_t)i * 262144, b2c + (size_t)i * 256, p0, nullptr, 2048, 256, 1024);
    if (i == 0)
      k_ln_add_bf<<<2048, 256, 0, stream>>>(x, p0, p1, l1g + 256, l1b + 256, h);
    else
      k_ln_out_add<<<2048, 256, 0, stream>>>(x, p0, p1, goc, beo, d_out, flags);
  }
}